// Round 1
// baseline (736.236 us; speedup 1.0000x reference)
//
#include <hip/hip_runtime.h>
#include <cstdint>

#define T_TOK 1024
#define HID   2048
#define NEXP  64
#define TOPK  8
#define INTER 768

typedef __attribute__((ext_vector_type(8))) short short8;   // 8 x bf16 (4 VGPRs)
typedef __attribute__((ext_vector_type(4))) float f32x4;

__device__ __forceinline__ unsigned short f2bf(float f){
  unsigned u = __float_as_uint(f);
  u += 0x7FFFu + ((u >> 16) & 1u);   // RNE; inputs are finite
  return (unsigned short)(u >> 16);
}

// ---------------- kernel 1: x (fp32) -> bf16 once per launch ----------------
__global__ void k_convert_x(const float* __restrict__ x, unsigned short* __restrict__ xbf){
  int gid = blockIdx.x * 256 + threadIdx.x;              // 262144 threads, 8 elems each
  const float4* src = (const float4*)(x + (size_t)gid * 8);
  float4 a = src[0], b = src[1];
  uint4 p;
  p.x = f2bf(a.x) | ((unsigned)f2bf(a.y) << 16);
  p.y = f2bf(a.z) | ((unsigned)f2bf(a.w) << 16);
  p.z = f2bf(b.x) | ((unsigned)f2bf(b.y) << 16);
  p.w = f2bf(b.z) | ((unsigned)f2bf(b.w) << 16);
  *(uint4*)(xbf + (size_t)gid * 8) = p;
}

// ---------------- kernel 2: router (fp32-exact logits, top-8) ----------------
__global__ void k_router(const float* __restrict__ x, const float* __restrict__ gw,
                         int* __restrict__ top_idx, float* __restrict__ top_w){
  int t = blockIdx.x;
  int tid = threadIdx.x;
  __shared__ float  xs[HID];
  __shared__ double part[4][NEXP];
  for (int i = tid; i < HID; i += 256) xs[i] = x[(size_t)t * HID + i];
  __syncthreads();
  int e = tid & 63, q = tid >> 6;
  double acc = 0.0;
  const float* gp = gw + e;
  #pragma unroll 8
  for (int h = q * 512; h < q * 512 + 512; ++h)
    acc += (double)xs[h] * (double)gp[(size_t)h * NEXP];
  part[q][e] = acc;
  __syncthreads();
  if (tid < 64){
    float logit = (float)(part[0][e] + part[1][e] + part[2][e] + part[3][e]);
    float cur = logit;
    float vals[TOPK]; int idxs[TOPK];
    #pragma unroll
    for (int k = 0; k < TOPK; ++k){
      float m = cur; int mi = e;
      #pragma unroll
      for (int off = 32; off > 0; off >>= 1){
        float ov = __shfl_xor(m, off);
        int   oi = __shfl_xor(mi, off);
        if (ov > m || (ov == m && oi < mi)){ m = ov; mi = oi; }   // jax tie-break: lower idx
      }
      vals[k] = m; idxs[k] = mi;
      if (e == mi) cur = -1e30f;
    }
    // renormalized softmax over the selected 8 == softmax of their logits
    float mx = vals[0], s = 0.f, ev[TOPK];
    #pragma unroll
    for (int k = 0; k < TOPK; ++k){ ev[k] = expf(vals[k] - mx); s += ev[k]; }
    #pragma unroll
    for (int k = 0; k < TOPK; ++k)
      if (e == k){ top_idx[t * TOPK + k] = idxs[k]; top_w[t * TOPK + k] = ev[k] / s; }
  }
}

// ---------------- kernel 3: per-expert histogram + exclusive scan ----------------
__global__ void k_hist(const int* __restrict__ top_idx, int* __restrict__ offs){
  __shared__ int hist[NEXP];
  int tid = threadIdx.x;
  if (tid < NEXP) hist[tid] = 0;
  __syncthreads();
  for (int j = tid; j < T_TOK * TOPK; j += 256) atomicAdd(&hist[top_idx[j]], 1);
  __syncthreads();
  if (tid == 0){
    int run = 0;
    for (int e = 0; e < NEXP; ++e){ offs[e] = run; run += hist[e]; }
    offs[NEXP] = run;   // == 8192
  }
}

// ---------------- kernel 4: deterministic ordered compaction ----------------
__global__ void k_compact(const int* __restrict__ top_idx, const float* __restrict__ top_w,
                          const int* __restrict__ offs, int* __restrict__ list_t,
                          float* __restrict__ list_w, int* __restrict__ slot_of){
  int e = blockIdx.x, tid = threadIdx.x;
  __shared__ int sc[256];
  int j0 = tid * 32, cnt = 0;
  for (int jj = 0; jj < 32; ++jj) cnt += (top_idx[j0 + jj] == e);
  sc[tid] = cnt; __syncthreads();
  for (int d = 1; d < 256; d <<= 1){
    int v = (tid >= d) ? sc[tid - d] : 0;
    __syncthreads();
    sc[tid] += v;
    __syncthreads();
  }
  int pos = offs[e] + sc[tid] - cnt;      // exclusive prefix, order-preserving
  for (int jj = 0; jj < 32; ++jj){
    int j = j0 + jj;
    if (top_idx[j] == e){
      list_t[pos]  = j >> 3;              // token
      list_w[pos]  = top_w[j];            // routing weight
      slot_of[j]   = pos;
      ++pos;
    }
  }
}

// ---------------- kernel 5: gate/up GEMM + SwiGLU (per expert) ----------------
// grid (12 i-tiles, 64 experts, 4 m-tiles of 256), block 512 = 8 waves.
// BM=256, BN=64 (both gate & up), BK=64; bf16 MFMA 16x16x32; XOR-swizzled LDS.
__global__ __launch_bounds__(512) void k_gateup(
    const unsigned short* __restrict__ xbf, const float* __restrict__ wg,
    const float* __restrict__ wu, const int* __restrict__ offs,
    const int* __restrict__ list_t, const float* __restrict__ list_w,
    unsigned short* __restrict__ act){
  int e  = blockIdx.y;
  int i0 = blockIdx.x * 64;
  int m0 = blockIdx.z * 256;
  int beg = offs[e], n_e = offs[e + 1] - beg;
  if (m0 >= n_e) return;
  int rows = n_e - m0; if (rows > 256) rows = 256;
  int tid = threadIdx.x, lane = tid & 63, wid = tid >> 6;

  __shared__ unsigned short lA[256 * 64];     // 32 KB, [row][k], swizzled
  __shared__ unsigned short lB[2][64 * 64];   // 16 KB, [i][k] transposed, swizzled
  __shared__ int   sTok[256];
  __shared__ float sWgt[256];
  if (tid < 256){
    int sl = beg + m0 + tid;
    if (tid < rows){ sTok[tid] = list_t[sl]; sWgt[tid] = list_w[sl]; }
    else           { sTok[tid] = list_t[beg]; sWgt[tid] = 0.f; }
  }
  __syncthreads();

  // staging assignment: A: thread -> row tid>>1, 64B half-row; B: lane = i col, wave = 8 k rows
  int arow  = tid >> 1;
  int cbase = (tid & 1) * 64;
  int aswz  = (arow & 7) << 4;
  int atok  = sTok[arow];
  uint4 rA[4];
  float rBv[2][8];

  auto loadA = [&](int k0){
    const char* src = (const char*)(xbf + (size_t)atok * HID + k0) + cbase;
    #pragma unroll
    for (int j = 0; j < 4; ++j) rA[j] = *(const uint4*)(src + j * 16);
  };
  auto loadB = [&](int k0){
    const float* g0 = wg + ((size_t)e * HID + k0 + wid * 8) * INTER + i0 + lane;
    const float* u0 = wu + ((size_t)e * HID + k0 + wid * 8) * INTER + i0 + lane;
    #pragma unroll
    for (int j = 0; j < 8; ++j){ rBv[0][j] = g0[(size_t)j * INTER]; rBv[1][j] = u0[(size_t)j * INTER]; }
  };
  auto storeLDS = [&](){
    #pragma unroll
    for (int j = 0; j < 4; ++j){
      int cb = cbase + j * 16;
      *(uint4*)((char*)lA + arow * 128 + (cb ^ aswz)) = rA[j];
    }
    int n = lane, nswz = (n & 7) << 4, kchunk = wid * 16;
    #pragma unroll
    for (int m = 0; m < 2; ++m){
      uint4 p;
      p.x = f2bf(rBv[m][0]) | ((unsigned)f2bf(rBv[m][1]) << 16);
      p.y = f2bf(rBv[m][2]) | ((unsigned)f2bf(rBv[m][3]) << 16);
      p.z = f2bf(rBv[m][4]) | ((unsigned)f2bf(rBv[m][5]) << 16);
      p.w = f2bf(rBv[m][6]) | ((unsigned)f2bf(rBv[m][7]) << 16);
      *(uint4*)((char*)&lB[m][0] + n * 128 + (kchunk ^ nswz)) = p;
    }
  };

  f32x4 accg[2][4] = {};
  f32x4 accu[2][4] = {};
  loadA(0); loadB(0);
  #pragma unroll 1
  for (int kt = 0; kt < HID / 64; ++kt){
    __syncthreads();
    storeLDS();
    __syncthreads();
    if (kt + 1 < HID / 64){ loadA((kt + 1) * 64); loadB((kt + 1) * 64); }  // fly under MFMAs
    int mbase = wid * 32;
    #pragma unroll
    for (int ks = 0; ks < 2; ++ks){
      int kbyte = ks * 64 + ((lane >> 4) << 4);
      int r0 = mbase + (lane & 15), r1 = r0 + 16;
      short8 a0 = *(const short8*)((const char*)lA + r0 * 128 + (kbyte ^ ((r0 & 7) << 4)));
      short8 a1 = *(const short8*)((const char*)lA + r1 * 128 + (kbyte ^ ((r1 & 7) << 4)));
      #pragma unroll
      for (int nf = 0; nf < 4; ++nf){
        int n = nf * 16 + (lane & 15);
        int nb = n * 128 + (kbyte ^ ((n & 7) << 4));
        short8 bg = *(const short8*)((const char*)&lB[0][0] + nb);
        short8 bu = *(const short8*)((const char*)&lB[1][0] + nb);
        accg[0][nf] = __builtin_amdgcn_mfma_f32_16x16x32_bf16(a0, bg, accg[0][nf], 0, 0, 0);
        accg[1][nf] = __builtin_amdgcn_mfma_f32_16x16x32_bf16(a1, bg, accg[1][nf], 0, 0, 0);
        accu[0][nf] = __builtin_amdgcn_mfma_f32_16x16x32_bf16(a0, bu, accu[0][nf], 0, 0, 0);
        accu[1][nf] = __builtin_amdgcn_mfma_f32_16x16x32_bf16(a1, bu, accu[1][nf], 0, 0, 0);
      }
    }
  }
  // epilogue: SwiGLU * routing weight -> bf16 activations
  #pragma unroll
  for (int mf = 0; mf < 2; ++mf){
    #pragma unroll
    for (int rr = 0; rr < 4; ++rr){
      int row = wid * 32 + mf * 16 + ((lane >> 4) << 2) + rr;
      if (row < rows){
        float wgt = sWgt[row];
        #pragma unroll
        for (int nf = 0; nf < 4; ++nf){
          float g = accg[mf][nf][rr], u = accu[mf][nf][rr];
          float h = (g / (1.f + expf(-g))) * u * wgt;
          act[(size_t)(beg + m0 + row) * INTER + i0 + nf * 16 + (lane & 15)] = f2bf(h);
        }
      }
    }
  }
}

// ---------------- kernel 6: down-proj GEMM (per expert) ----------------
// grid (32 h-tiles, 64 experts, 4 m-tiles of 256), block 512 = 8 waves. K = 768.
__global__ __launch_bounds__(512) void k_down(
    const unsigned short* __restrict__ act, const float* __restrict__ wd,
    const int* __restrict__ offs, const int* __restrict__ list_t,
    float* __restrict__ contrib, float* __restrict__ out, int atomicMode){
  int e  = blockIdx.y;
  int n0 = blockIdx.x * 64;
  int m0 = blockIdx.z * 256;
  int beg = offs[e], n_e = offs[e + 1] - beg;
  if (m0 >= n_e) return;
  int rows = n_e - m0; if (rows > 256) rows = 256;
  int tid = threadIdx.x, lane = tid & 63, wid = tid >> 6;

  __shared__ unsigned short lA[256 * 64];   // 32 KB
  __shared__ unsigned short lB[64 * 64];    // 8 KB, [h][k] transposed, swizzled
  __shared__ int sTok[256];
  if (tid < 256){
    int sl = beg + m0 + tid;
    sTok[tid] = (tid < rows) ? list_t[sl] : 0;
  }
  __syncthreads();

  int arow  = tid >> 1;
  int cbase = (tid & 1) * 64;
  int aswz  = (arow & 7) << 4;
  int aslot = beg + m0 + arow; if (aslot > T_TOK * TOPK - 1) aslot = T_TOK * TOPK - 1;
  uint4 rA[4];
  float rBv[8];

  auto loadA = [&](int k0){
    const char* src = (const char*)(act + (size_t)aslot * INTER + k0) + cbase;
    #pragma unroll
    for (int j = 0; j < 4; ++j) rA[j] = *(const uint4*)(src + j * 16);
  };
  auto loadB = [&](int k0){
    const float* b0 = wd + ((size_t)e * INTER + k0 + wid * 8) * HID + n0 + lane;
    #pragma unroll
    for (int j = 0; j < 8; ++j) rBv[j] = b0[(size_t)j * HID];
  };
  auto storeLDS = [&](){
    #pragma unroll
    for (int j = 0; j < 4; ++j){
      int cb = cbase + j * 16;
      *(uint4*)((char*)lA + arow * 128 + (cb ^ aswz)) = rA[j];
    }
    int n = lane, nswz = (n & 7) << 4, kchunk = wid * 16;
    uint4 p;
    p.x = f2bf(rBv[0]) | ((unsigned)f2bf(rBv[1]) << 16);
    p.y = f2bf(rBv[2]) | ((unsigned)f2bf(rBv[3]) << 16);
    p.z = f2bf(rBv[4]) | ((unsigned)f2bf(rBv[5]) << 16);
    p.w = f2bf(rBv[6]) | ((unsigned)f2bf(rBv[7]) << 16);
    *(uint4*)((char*)lB + n * 128 + (kchunk ^ nswz)) = p;
  };

  f32x4 acc[2][4] = {};
  loadA(0); loadB(0);
  #pragma unroll 1
  for (int kt = 0; kt < INTER / 64; ++kt){
    __syncthreads();
    storeLDS();
    __syncthreads();
    if (kt + 1 < INTER / 64){ loadA((kt + 1) * 64); loadB((kt + 1) * 64); }
    int mbase = wid * 32;
    #pragma unroll
    for (int ks = 0; ks < 2; ++ks){
      int kbyte = ks * 64 + ((lane >> 4) << 4);
      int r0 = mbase + (lane & 15), r1 = r0 + 16;
      short8 a0 = *(const short8*)((const char*)lA + r0 * 128 + (kbyte ^ ((r0 & 7) << 4)));
      short8 a1 = *(const short8*)((const char*)lA + r1 * 128 + (kbyte ^ ((r1 & 7) << 4)));
      #pragma unroll
      for (int nf = 0; nf < 4; ++nf){
        int n = nf * 16 + (lane & 15);
        int nb = n * 128 + (kbyte ^ ((n & 7) << 4));
        short8 b = *(const short8*)((const char*)lB + nb);
        acc[0][nf] = __builtin_amdgcn_mfma_f32_16x16x32_bf16(a0, b, acc[0][nf], 0, 0, 0);
        acc[1][nf] = __builtin_amdgcn_mfma_f32_16x16x32_bf16(a1, b, acc[1][nf], 0, 0, 0);
      }
    }
  }
  #pragma unroll
  for (int mf = 0; mf < 2; ++mf){
    #pragma unroll
    for (int rr = 0; rr < 4; ++rr){
      int row = wid * 32 + mf * 16 + ((lane >> 4) << 2) + rr;
      if (row < rows){
        #pragma unroll
        for (int nf = 0; nf < 4; ++nf){
          float v = acc[mf][nf][rr];
          int h = n0 + nf * 16 + (lane & 15);
          if (atomicMode) atomicAdd(&out[(size_t)sTok[row] * HID + h], v);
          else            contrib[(size_t)(beg + m0 + row) * HID + h] = v;
        }
      }
    }
  }
}

// ---------------- kernel 7: deterministic 8-way combine ----------------
__global__ void k_reduce(const float* __restrict__ contrib, const int* __restrict__ slot_of,
                         float* __restrict__ out){
  int bx = blockIdx.x;                 // 2048 blocks: (token, half-row)
  int t = bx >> 1, seg = bx & 1, tid = threadIdx.x;
  __shared__ int ss[TOPK];
  if (tid < TOPK) ss[tid] = slot_of[t * TOPK + tid];
  __syncthreads();
  int h = (seg * 256 + tid) * 4;
  f32x4 s = {0.f, 0.f, 0.f, 0.f};
  #pragma unroll
  for (int k = 0; k < TOPK; ++k){
    f32x4 v = *(const f32x4*)(contrib + (size_t)ss[k] * HID + h);
    s += v;
  }
  *(f32x4*)(out + (size_t)t * HID + h) = s;
}

extern "C" void kernel_launch(void* const* d_in, const int* in_sizes, int n_in,
                              void* d_out, int out_size, void* d_ws, size_t ws_size,
                              hipStream_t stream){
  const float* x   = (const float*)d_in[0];
  const float* gw  = (const float*)d_in[1];
  const float* wgp = (const float*)d_in[2];
  const float* wup = (const float*)d_in[3];
  const float* wdp = (const float*)d_in[4];
  float* out = (float*)d_out;
  char* ws = (char*)d_ws;

  // workspace layout (bytes)
  int*   top_idx = (int*)  (ws + 0);          //  32 KB
  float* top_w   = (float*)(ws + 32768);      //  32 KB
  int*   offs    = (int*)  (ws + 65536);      //  4 KB region
  int*   list_t  = (int*)  (ws + 69632);      //  32 KB
  float* list_w  = (float*)(ws + 102400);     //  32 KB
  int*   slot_of = (int*)  (ws + 135168);     //  32 KB
  unsigned short* xbf = (unsigned short*)(ws + 167936);             // 4 MB
  unsigned short* act = (unsigned short*)(ws + 167936 + 4194304);   // 12 MB
  float* contrib = (float*)(ws + 167936 + 4194304 + 12582912);      // 64 MB
  size_t need_full = (size_t)167936 + 4194304 + 12582912 + 67108864;
  int atomicMode = (ws_size < need_full) ? 1 : 0;

  k_convert_x<<<1024, 256, 0, stream>>>(x, xbf);
  k_router   <<<1024, 256, 0, stream>>>(x, gw, top_idx, top_w);
  k_hist     <<<1,    256, 0, stream>>>(top_idx, offs);
  k_compact  <<<64,   256, 0, stream>>>(top_idx, top_w, offs, list_t, list_w, slot_of);
  k_gateup   <<<dim3(INTER / 64, NEXP, 4), 512, 0, stream>>>(xbf, wgp, wup, offs, list_t, list_w, act);
  if (atomicMode){
    hipMemsetAsync(d_out, 0, (size_t)out_size * sizeof(float), stream);
    k_down  <<<dim3(HID / 64, NEXP, 4), 512, 0, stream>>>(act, wdp, offs, list_t, contrib, out, 1);
  } else {
    k_down  <<<dim3(HID / 64, NEXP, 4), 512, 0, stream>>>(act, wdp, offs, list_t, contrib, out, 0);
    k_reduce<<<2048, 256, 0, stream>>>(contrib, slot_of, out);
  }
}

// Round 2
// 391.332 us; speedup vs baseline: 1.8814x; 1.8814x over previous
//
#include <hip/hip_runtime.h>
#include <cstdint>

#define T_TOK 1024
#define HID   2048
#define NEXP  64
#define TOPK  8
#define INTER 768

typedef __attribute__((ext_vector_type(8))) short short8;   // 8 x bf16 (4 VGPRs)
typedef __attribute__((ext_vector_type(4))) float f32x4;

__device__ __forceinline__ unsigned short f2bf(float f){
  unsigned u = __float_as_uint(f);
  u += 0x7FFFu + ((u >> 16) & 1u);   // RNE; inputs are finite
  return (unsigned short)(u >> 16);
}

// ---------------- kernel 1: x (fp32) -> bf16 once per launch ----------------
__global__ void k_convert_x(const float* __restrict__ x, unsigned short* __restrict__ xbf){
  int gid = blockIdx.x * 256 + threadIdx.x;
  const float4* src = (const float4*)(x + (size_t)gid * 8);
  float4 a = src[0], b = src[1];
  uint4 p;
  p.x = f2bf(a.x) | ((unsigned)f2bf(a.y) << 16);
  p.y = f2bf(a.z) | ((unsigned)f2bf(a.w) << 16);
  p.z = f2bf(b.x) | ((unsigned)f2bf(b.y) << 16);
  p.w = f2bf(b.z) | ((unsigned)f2bf(b.w) << 16);
  *(uint4*)(xbf + (size_t)gid * 8) = p;
}

// ---------------- kernel 2: router (fp32-exact logits, top-8) ----------------
__global__ void k_router(const float* __restrict__ x, const float* __restrict__ gw,
                         int* __restrict__ top_idx, float* __restrict__ top_w){
  int t = blockIdx.x;
  int tid = threadIdx.x;
  __shared__ float  xs[HID];
  __shared__ double part[4][NEXP];
  for (int i = tid; i < HID; i += 256) xs[i] = x[(size_t)t * HID + i];
  __syncthreads();
  int e = tid & 63, q = tid >> 6;
  double acc = 0.0;
  const float* gp = gw + e;
  #pragma unroll 8
  for (int h = q * 512; h < q * 512 + 512; ++h)
    acc += (double)xs[h] * (double)gp[(size_t)h * NEXP];
  part[q][e] = acc;
  __syncthreads();
  if (tid < 64){
    float logit = (float)(part[0][e] + part[1][e] + part[2][e] + part[3][e]);
    float cur = logit;
    float vals[TOPK]; int idxs[TOPK];
    #pragma unroll
    for (int k = 0; k < TOPK; ++k){
      float m = cur; int mi = e;
      #pragma unroll
      for (int off = 32; off > 0; off >>= 1){
        float ov = __shfl_xor(m, off);
        int   oi = __shfl_xor(mi, off);
        if (ov > m || (ov == m && oi < mi)){ m = ov; mi = oi; }
      }
      vals[k] = m; idxs[k] = mi;
      if (e == mi) cur = -1e30f;
    }
    float mx = vals[0], s = 0.f, ev[TOPK];
    #pragma unroll
    for (int k = 0; k < TOPK; ++k){ ev[k] = expf(vals[k] - mx); s += ev[k]; }
    #pragma unroll
    for (int k = 0; k < TOPK; ++k)
      if (e == k){ top_idx[t * TOPK + k] = idxs[k]; top_w[t * TOPK + k] = ev[k] / s; }
  }
}

// ---------------- kernel 3: per-expert histogram + exclusive scan ----------------
__global__ void k_hist(const int* __restrict__ top_idx, int* __restrict__ offs){
  __shared__ int hist[NEXP];
  int tid = threadIdx.x;
  if (tid < NEXP) hist[tid] = 0;
  __syncthreads();
  for (int j = tid; j < T_TOK * TOPK; j += 256) atomicAdd(&hist[top_idx[j]], 1);
  __syncthreads();
  if (tid == 0){
    int run = 0;
    for (int e = 0; e < NEXP; ++e){ offs[e] = run; run += hist[e]; }
    offs[NEXP] = run;
  }
}

// ---------------- kernel 4: deterministic ordered compaction ----------------
__global__ void k_compact(const int* __restrict__ top_idx, const float* __restrict__ top_w,
                          const int* __restrict__ offs, int* __restrict__ list_t,
                          float* __restrict__ list_w, int* __restrict__ slot_of){
  int e = blockIdx.x, tid = threadIdx.x;
  __shared__ int sc[256];
  int j0 = tid * 32, cnt = 0;
  for (int jj = 0; jj < 32; ++jj) cnt += (top_idx[j0 + jj] == e);
  sc[tid] = cnt; __syncthreads();
  for (int d = 1; d < 256; d <<= 1){
    int v = (tid >= d) ? sc[tid - d] : 0;
    __syncthreads();
    sc[tid] += v;
    __syncthreads();
  }
  int pos = offs[e] + sc[tid] - cnt;
  for (int jj = 0; jj < 32; ++jj){
    int j = j0 + jj;
    if (top_idx[j] == e){
      list_t[pos]  = j >> 3;
      list_w[pos]  = top_w[j];
      slot_of[j]   = pos;
      ++pos;
    }
  }
}

#define BARRIER() do { asm volatile("s_waitcnt lgkmcnt(0)" ::: "memory"); \
                       __builtin_amdgcn_s_barrier(); } while (0)

// ---------------- kernel 5: gate/up GEMM + SwiGLU ----------------
// BM=192 (whole expert), BN=64i x {gate,up}, BK=64. 512 thr = 8 waves (4m x 2n).
// B: reg ping-pong + LDS dbuf, depth-2 prefetch, raw barriers (counted vmcnt by compiler).
// A: bf16 fragments loaded straight from global (L2/L3-resident xbf).
__global__ __launch_bounds__(512) void k_gateup(
    const unsigned short* __restrict__ xbf, const float* __restrict__ wg,
    const float* __restrict__ wu, const int* __restrict__ offs,
    const int* __restrict__ list_t, const float* __restrict__ list_w,
    unsigned short* __restrict__ act){
  const int KT = HID / 64;                   // 32 k-tiles
  int e  = blockIdx.y;
  int i0 = blockIdx.x * 64;
  int beg = offs[e], n_e = offs[e + 1] - beg;
  if (n_e <= 0) return;
  int tid = threadIdx.x, lane = tid & 63, wid = tid >> 6;
  int wm = wid & 3, wn = wid >> 2;           // 48-row m-quarter, 32-col n-half

  __shared__ unsigned short lB[2][2][64 * 64];   // [buf][mat][i*64k] swizzled, 32 KB

  // B staging: thread -> (i col = tid&63, k-group = tid>>6 of 8 k-rows)
  int bi = tid & 63, bg = tid >> 6;
  int bswz = (bi & 7) << 4;
  const float* gBase = wg + (size_t)e * HID * INTER + i0 + bi;
  const float* uBase = wu + (size_t)e * HID * INTER + i0 + bi;

#define GU_ISSUE_B(t, rg, ru) { \
    const float* _gp = gBase + (size_t)((t) * 64 + bg * 8) * INTER; \
    const float* _up = uBase + (size_t)((t) * 64 + bg * 8) * INTER; \
    _Pragma("unroll") for (int j = 0; j < 8; ++j){ \
      rg[j] = _gp[(size_t)j * INTER]; ru[j] = _up[(size_t)j * INTER]; } }

#define GU_WRITE_B(buf, rg, ru) { \
    uint4 _p; \
    _p.x = f2bf(rg[0]) | ((unsigned)f2bf(rg[1]) << 16); \
    _p.y = f2bf(rg[2]) | ((unsigned)f2bf(rg[3]) << 16); \
    _p.z = f2bf(rg[4]) | ((unsigned)f2bf(rg[5]) << 16); \
    _p.w = f2bf(rg[6]) | ((unsigned)f2bf(rg[7]) << 16); \
    *(uint4*)((char*)&lB[buf][0][0] + bi * 128 + ((bg * 16) ^ bswz)) = _p; \
    _p.x = f2bf(ru[0]) | ((unsigned)f2bf(ru[1]) << 16); \
    _p.y = f2bf(ru[2]) | ((unsigned)f2bf(ru[3]) << 16); \
    _p.z = f2bf(ru[4]) | ((unsigned)f2bf(ru[5]) << 16); \
    _p.w = f2bf(ru[6]) | ((unsigned)f2bf(ru[7]) << 16); \
    *(uint4*)((char*)&lB[buf][1][0] + bi * 128 + ((bg * 16) ^ bswz)) = _p; }

#define GU_ISSUE_A(t, ra) { \
    int _kk = (t) * 64 + ((lane >> 4) << 3); \
    _Pragma("unroll") for (int mf = 0; mf < 3; ++mf){ \
      const unsigned short* _ap = xbf + (size_t)tokA[mf] * HID + _kk; \
      ra[mf][0] = *(const short8*)_ap; \
      ra[mf][1] = *(const short8*)(_ap + 32); } }

#define GU_MFMA(buf, ra) { \
    _Pragma("unroll") for (int ks = 0; ks < 2; ++ks){ \
      short8 _bf[2][2]; \
      _Pragma("unroll") for (int nf = 0; nf < 2; ++nf){ \
        int _il = wn * 32 + nf * 16 + (lane & 15); \
        int _kb = (ks * 64 + ((lane >> 4) << 4)) ^ ((_il & 7) << 4); \
        _bf[0][nf] = *(const short8*)((const char*)&lB[buf][0][0] + _il * 128 + _kb); \
        _bf[1][nf] = *(const short8*)((const char*)&lB[buf][1][0] + _il * 128 + _kb); } \
      _Pragma("unroll") for (int mf = 0; mf < 3; ++mf) \
        _Pragma("unroll") for (int nf = 0; nf < 2; ++nf){ \
          accg[mf][nf] = __builtin_amdgcn_mfma_f32_16x16x32_bf16(ra[mf][ks], _bf[0][nf], accg[mf][nf], 0, 0, 0); \
          accu[mf][nf] = __builtin_amdgcn_mfma_f32_16x16x32_bf16(ra[mf][ks], _bf[1][nf], accu[mf][nf], 0, 0, 0); } } }

  for (int m0 = 0; m0 < n_e; m0 += 192){
    int tokA[3];
    #pragma unroll
    for (int mf = 0; mf < 3; ++mf){
      int r = wm * 48 + mf * 16 + (lane & 15);
      tokA[mf] = list_t[(m0 + r < n_e) ? (beg + m0 + r) : beg];
    }
    float rbg0[8], rbu0[8], rbg1[8], rbu1[8];
    short8 rA0[3][2], rA1[3][2];
    f32x4 accg[3][2] = {}; f32x4 accu[3][2] = {};

    GU_ISSUE_B(0, rbg0, rbu0);
    GU_ISSUE_B(1, rbg1, rbu1);
    GU_ISSUE_A(0, rA0);
    GU_WRITE_B(0, rbg0, rbu0);
    BARRIER();
    #pragma unroll 1
    for (int t = 0; t < KT - 2; t += 2){
      GU_ISSUE_A(t + 1, rA1);
      GU_ISSUE_B(t + 2, rbg0, rbu0);
      GU_MFMA(0, rA0);
      GU_WRITE_B(1, rbg1, rbu1);
      BARRIER();
      GU_ISSUE_A(t + 2, rA0);
      if (t + 3 < KT) { GU_ISSUE_B(t + 3, rbg1, rbu1); }
      GU_MFMA(1, rA1);
      GU_WRITE_B(0, rbg0, rbu0);
      BARRIER();
    }
    GU_ISSUE_A(KT - 1, rA1);
    GU_MFMA(0, rA0);
    GU_WRITE_B(1, rbg1, rbu1);
    BARRIER();
    GU_MFMA(1, rA1);

    // epilogue: SwiGLU * routing weight -> bf16
    #pragma unroll
    for (int mf = 0; mf < 3; ++mf){
      #pragma unroll
      for (int rr = 0; rr < 4; ++rr){
        int r = wm * 48 + mf * 16 + ((lane >> 4) << 2) + rr;
        if (m0 + r < n_e){
          int slot = beg + m0 + r;
          float wgt = list_w[slot];
          #pragma unroll
          for (int nf = 0; nf < 2; ++nf){
            float g = accg[mf][nf][rr], u = accu[mf][nf][rr];
            float h = (g / (1.f + expf(-g))) * u * wgt;
            act[(size_t)slot * INTER + i0 + wn * 32 + nf * 16 + (lane & 15)] = f2bf(h);
          }
        }
      }
    }
    if (m0 + 192 < n_e) BARRIER();   // re-sync before reusing LDS (never taken in practice)
  }
}

// ---------------- kernel 6: down-proj GEMM ----------------
// BM=192, BN=128 h-cols, BK=64, K=768 (12 tiles). Same pipeline as k_gateup.
__global__ __launch_bounds__(512) void k_down(
    const unsigned short* __restrict__ act, const float* __restrict__ wd,
    const int* __restrict__ offs, const int* __restrict__ list_t,
    float* __restrict__ contrib, float* __restrict__ out, int atomicMode){
  const int KT = INTER / 64;                 // 12 k-tiles
  int e  = blockIdx.y;
  int n0 = blockIdx.x * 128;
  int beg = offs[e], n_e = offs[e + 1] - beg;
  if (n_e <= 0) return;
  int tid = threadIdx.x, lane = tid & 63, wid = tid >> 6;
  int wm = wid & 3, wn = wid >> 2;           // 48-row m-quarter, 64-col n-half

  __shared__ unsigned short lB[2][128 * 64]; // [buf][h*64k] swizzled, 32 KB

  int bh = tid & 127, bg = tid >> 7;         // h col, k-group (4 groups x 8 k, x2 halves)
  int hswz = (bh & 7) << 4;
  const float* dBase = wd + (size_t)e * INTER * HID + n0 + bh;

#define DN_ISSUE_B(t, rb) { \
    const float* _p = dBase + (size_t)((t) * 64 + bg * 8) * HID; \
    _Pragma("unroll") for (int j = 0; j < 8; ++j){ \
      rb[j] = _p[(size_t)j * HID]; rb[8 + j] = _p[(size_t)(j + 32) * HID]; } }

#define DN_WRITE_B(buf, rb) { \
    uint4 _p; \
    _p.x = f2bf(rb[0]) | ((unsigned)f2bf(rb[1]) << 16); \
    _p.y = f2bf(rb[2]) | ((unsigned)f2bf(rb[3]) << 16); \
    _p.z = f2bf(rb[4]) | ((unsigned)f2bf(rb[5]) << 16); \
    _p.w = f2bf(rb[6]) | ((unsigned)f2bf(rb[7]) << 16); \
    *(uint4*)((char*)&lB[buf][0] + bh * 128 + ((bg * 16) ^ hswz)) = _p; \
    _p.x = f2bf(rb[8])  | ((unsigned)f2bf(rb[9])  << 16); \
    _p.y = f2bf(rb[10]) | ((unsigned)f2bf(rb[11]) << 16); \
    _p.z = f2bf(rb[12]) | ((unsigned)f2bf(rb[13]) << 16); \
    _p.w = f2bf(rb[14]) | ((unsigned)f2bf(rb[15]) << 16); \
    *(uint4*)((char*)&lB[buf][0] + bh * 128 + ((bg * 16 + 64) ^ hswz)) = _p; }

#define DN_ISSUE_A(t, ra) { \
    int _kk = (t) * 64 + ((lane >> 4) << 3); \
    _Pragma("unroll") for (int mf = 0; mf < 3; ++mf){ \
      const unsigned short* _ap = act + (size_t)aslot[mf] * INTER + _kk; \
      ra[mf][0] = *(const short8*)_ap; \
      ra[mf][1] = *(const short8*)(_ap + 32); } }

#define DN_MFMA(buf, ra) { \
    _Pragma("unroll") for (int ks = 0; ks < 2; ++ks){ \
      short8 _bf[4]; \
      _Pragma("unroll") for (int nf = 0; nf < 4; ++nf){ \
        int _il = wn * 64 + nf * 16 + (lane & 15); \
        int _kb = (ks * 64 + ((lane >> 4) << 4)) ^ ((_il & 7) << 4); \
        _bf[nf] = *(const short8*)((const char*)&lB[buf][0] + _il * 128 + _kb); } \
      _Pragma("unroll") for (int mf = 0; mf < 3; ++mf) \
        _Pragma("unroll") for (int nf = 0; nf < 4; ++nf) \
          acc[mf][nf] = __builtin_amdgcn_mfma_f32_16x16x32_bf16(ra[mf][ks], _bf[nf], acc[mf][nf], 0, 0, 0); } }

  for (int m0 = 0; m0 < n_e; m0 += 192){
    int aslot[3];
    #pragma unroll
    for (int mf = 0; mf < 3; ++mf){
      int r = wm * 48 + mf * 16 + (lane & 15);
      aslot[mf] = (m0 + r < n_e) ? (beg + m0 + r) : beg;
    }
    float rb0[16], rb1[16];
    short8 rA0[3][2], rA1[3][2];
    f32x4 acc[3][4] = {};

    DN_ISSUE_B(0, rb0);
    DN_ISSUE_B(1, rb1);
    DN_ISSUE_A(0, rA0);
    DN_WRITE_B(0, rb0);
    BARRIER();
    #pragma unroll 1
    for (int t = 0; t < KT - 2; t += 2){
      DN_ISSUE_A(t + 1, rA1);
      DN_ISSUE_B(t + 2, rb0);
      DN_MFMA(0, rA0);
      DN_WRITE_B(1, rb1);
      BARRIER();
      DN_ISSUE_A(t + 2, rA0);
      if (t + 3 < KT) { DN_ISSUE_B(t + 3, rb1); }
      DN_MFMA(1, rA1);
      DN_WRITE_B(0, rb0);
      BARRIER();
    }
    DN_ISSUE_A(KT - 1, rA1);
    DN_MFMA(0, rA0);
    DN_WRITE_B(1, rb1);
    BARRIER();
    DN_MFMA(1, rA1);

    #pragma unroll
    for (int mf = 0; mf < 3; ++mf){
      #pragma unroll
      for (int rr = 0; rr < 4; ++rr){
        int r = wm * 48 + mf * 16 + ((lane >> 4) << 2) + rr;
        if (m0 + r < n_e){
          int slot = beg + m0 + r;
          #pragma unroll
          for (int nf = 0; nf < 4; ++nf){
            float v = acc[mf][nf][rr];
            int h = n0 + wn * 64 + nf * 16 + (lane & 15);
            if (atomicMode) atomicAdd(&out[(size_t)list_t[slot] * HID + h], v);
            else            contrib[(size_t)slot * HID + h] = v;
          }
        }
      }
    }
    if (m0 + 192 < n_e) BARRIER();
  }
}

// ---------------- kernel 7: deterministic 8-way combine ----------------
__global__ void k_reduce(const float* __restrict__ contrib, const int* __restrict__ slot_of,
                         float* __restrict__ out){
  int bx = blockIdx.x;
  int t = bx >> 1, seg = bx & 1, tid = threadIdx.x;
  __shared__ int ss[TOPK];
  if (tid < TOPK) ss[tid] = slot_of[t * TOPK + tid];
  __syncthreads();
  int h = (seg * 256 + tid) * 4;
  f32x4 s = {0.f, 0.f, 0.f, 0.f};
  #pragma unroll
  for (int k = 0; k < TOPK; ++k){
    f32x4 v = *(const f32x4*)(contrib + (size_t)ss[k] * HID + h);
    s += v;
  }
  *(f32x4*)(out + (size_t)t * HID + h) = s;
}

extern "C" void kernel_launch(void* const* d_in, const int* in_sizes, int n_in,
                              void* d_out, int out_size, void* d_ws, size_t ws_size,
                              hipStream_t stream){
  const float* x   = (const float*)d_in[0];
  const float* gw  = (const float*)d_in[1];
  const float* wgp = (const float*)d_in[2];
  const float* wup = (const float*)d_in[3];
  const float* wdp = (const float*)d_in[4];
  float* out = (float*)d_out;
  char* ws = (char*)d_ws;

  int*   top_idx = (int*)  (ws + 0);
  float* top_w   = (float*)(ws + 32768);
  int*   offs    = (int*)  (ws + 65536);
  int*   list_t  = (int*)  (ws + 69632);
  float* list_w  = (float*)(ws + 102400);
  int*   slot_of = (int*)  (ws + 135168);
  unsigned short* xbf = (unsigned short*)(ws + 167936);             // 4 MB
  unsigned short* act = (unsigned short*)(ws + 167936 + 4194304);   // 12 MB
  float* contrib = (float*)(ws + 167936 + 4194304 + 12582912);      // 64 MB
  size_t need_full = (size_t)167936 + 4194304 + 12582912 + 67108864;
  int atomicMode = (ws_size < need_full) ? 1 : 0;

  k_convert_x<<<1024, 256, 0, stream>>>(x, xbf);
  k_router   <<<1024, 256, 0, stream>>>(x, gw, top_idx, top_w);
  k_hist     <<<1,    256, 0, stream>>>(top_idx, offs);
  k_compact  <<<64,   256, 0, stream>>>(top_idx, top_w, offs, list_t, list_w, slot_of);
  k_gateup   <<<dim3(INTER / 64, NEXP), 512, 0, stream>>>(xbf, wgp, wup, offs, list_t, list_w, act);
  if (atomicMode){
    hipMemsetAsync(d_out, 0, (size_t)out_size * sizeof(float), stream);
    k_down  <<<dim3(HID / 128, NEXP), 512, 0, stream>>>(act, wdp, offs, list_t, contrib, out, 1);
  } else {
    k_down  <<<dim3(HID / 128, NEXP), 512, 0, stream>>>(act, wdp, offs, list_t, contrib, out, 0);
    k_reduce<<<2048, 256, 0, stream>>>(contrib, slot_of, out);
  }
}